// Round 10
// baseline (519.225 us; speedup 1.0000x reference)
//
#include <hip/hip_runtime.h>

#define NN 8192
#define NFEAT 512
#define NHID 128
#define NCLASS 16
#define CAP 128
#define K1_BLOCKS (NN / 4)    // 2048: one row per wave, 4 waves/block
#define K2_BLOCKS (NN / 16)   // 512

__device__ __forceinline__ int mbcnt64(unsigned long long m) {
  return __builtin_amdgcn_mbcnt_hi((unsigned int)(m >> 32),
         __builtin_amdgcn_mbcnt_lo((unsigned int)m, 0));
}

// ---------------------------------------------------------------------------
// Fused kernel A:
//   blocks [0, K1_BLOCKS):  wave-per-row adjacency compaction. No LDS, no
//     atomics, no barriers: per 256-col chunk, ballot mask -> slot = running
//     wave-uniform base + popcount-of-lower-lanes; direct scattered store.
//     (Column order within a row is arbitrary; the consumer only sums.)
//   blocks [K1_BLOCKS, +K2_BLOCKS): xw = x @ W1 (16 rows/block), overlaps
//     the HBM-bound scan on idle CUs.
// ---------------------------------------------------------------------------
__global__ __launch_bounds__(256) void kA(const float* __restrict__ adj,
                                          const float* __restrict__ x,
                                          const float* __restrict__ W1,
                                          int* __restrict__ rowcnt,
                                          int* __restrict__ cols,
                                          float* __restrict__ dinv,
                                          float* __restrict__ xw) {
  if (blockIdx.x < K1_BLOCKS) {
    // ---- k1: wave-per-row compaction ----
    int lane = threadIdx.x & 63;
    int row = blockIdx.x * 4 + (threadIdx.x >> 6);
    const float4* arow = (const float4*)(adj + (size_t)row * NN);
    int* crow = cols + (size_t)row * CAP;
    int wbase = 0;                      // wave-uniform running count (SGPR)
    for (int i = 0; i < 4; ++i) {       // 4 x 8KB sweeps of the 32KB row
      float4 v[8];
#pragma unroll
      for (int u = 0; u < 8; ++u)
        v[u] = arow[i * 512 + u * 64 + lane];   // 8 loads in flight
#pragma unroll
      for (int u = 0; u < 8; ++u) {
        int cbase = (i * 512 + u * 64 + lane) * 4;
#pragma unroll
        for (int e = 0; e < 4; ++e) {
          float ve = (e == 0) ? v[u].x : (e == 1) ? v[u].y
                   : (e == 2) ? v[u].z : v[u].w;
          unsigned long long m = __ballot(ve != 0.0f);
          if (ve != 0.0f) {
            int pos = wbase + mbcnt64(m);
            if (pos < CAP) crow[pos] = cbase + e;
          }
          wbase += __popcll(m);
        }
      }
    }
    if (lane == 0) {
      rowcnt[row] = min(wbase, CAP);
      dinv[row] = rsqrtf((float)wbase + 1.0f);
    }
  } else {
    // ---- k2: xw = x @ W1 ----
    int blk = blockIdx.x - K1_BLOCKS;
    int p = threadIdx.x & 127;
    int g = threadIdx.x >> 7;                 // 0..1
    int rbase = blk * 16 + g * 8;
    const float* xr0 = x + (size_t)rbase * NFEAT;
    float acc[8] = {};
    for (int k = 0; k < NFEAT; k += 4) {
      float4 xv[8];
#pragma unroll
      for (int r = 0; r < 8; ++r)
        xv[r] = *(const float4*)(xr0 + (size_t)r * NFEAT + k);
#pragma unroll
      for (int t = 0; t < 4; ++t) {
        float w = W1[(size_t)(k + t) * NHID + p];
#pragma unroll
        for (int r = 0; r < 8; ++r) {
          float xe = (t == 0) ? xv[r].x : (t == 1) ? xv[r].y
                   : (t == 2) ? xv[r].z : xv[r].w;
          acc[r] = fmaf(xe, w, acc[r]);
        }
      }
    }
#pragma unroll
    for (int r = 0; r < 8; ++r)
      xw[(size_t)(rbase + r) * NHID + p] = acc[r];
  }
}

// ---------------------------------------------------------------------------
// Kernel B (fused gc1+relu+gc2-matmul): h_row = relu(A_norm @ xw + b1) in LDS,
// then hw_row = h_row @ W2 via per-block partial reduction. Block = one row.
// ---------------------------------------------------------------------------
__global__ __launch_bounds__(128) void kB(const float* __restrict__ xw,
                                          const int* __restrict__ rowcnt,
                                          const int* __restrict__ cols,
                                          const float* __restrict__ dinv,
                                          const float* __restrict__ b1,
                                          const float* __restrict__ W2,
                                          float* __restrict__ hw) {
  __shared__ int   sj[CAP];
  __shared__ float sw[CAP];
  __shared__ float sh[NHID];
  __shared__ float part[128];
  int row = blockIdx.x;
  int c = threadIdx.x;
  int cnt = rowcnt[row];
  const int* crow = cols + (size_t)row * CAP;
  if (c < cnt) { int j = crow[c]; sj[c] = j; sw[c] = dinv[j]; }
  __syncthreads();
  float di = dinv[row];
  float acc = di * xw[(size_t)row * NHID + c];   // self-loop (I) term
  int e = 0;
  for (; e + 4 <= cnt; e += 4) {
    int j0 = sj[e], j1 = sj[e + 1], j2 = sj[e + 2], j3 = sj[e + 3];
    float w0 = sw[e], w1 = sw[e + 1], w2 = sw[e + 2], w3 = sw[e + 3];
    float v0 = xw[(size_t)j0 * NHID + c];
    float v1 = xw[(size_t)j1 * NHID + c];
    float v2 = xw[(size_t)j2 * NHID + c];
    float v3 = xw[(size_t)j3 * NHID + c];
    acc = fmaf(w0, v0, acc);
    acc = fmaf(w1, v1, acc);
    acc = fmaf(w2, v2, acc);
    acc = fmaf(w3, v3, acc);
  }
  for (; e < cnt; ++e) acc = fmaf(sw[e], xw[(size_t)sj[e] * NHID + c], acc);
  float h = fmaxf(fmaf(di, acc, b1[c]), 0.0f);
  sh[c] = h;
  __syncthreads();
  int cc = c & 15, seg = c >> 4;
  float pacc = 0.0f;
#pragma unroll
  for (int kk = 0; kk < 16; ++kk) {
    int k = seg * 16 + kk;
    pacc = fmaf(sh[k], W2[(size_t)k * NCLASS + cc], pacc);
  }
  part[c] = pacc;
  __syncthreads();
  if (c < 16) {
    float s = 0.0f;
#pragma unroll
    for (int sg = 0; sg < 8; ++sg) s += part[c + 16 * sg];
    hw[(size_t)row * NCLASS + c] = s;
  }
}

// ---------------------------------------------------------------------------
// Kernel C: out = log_softmax(A_norm @ hw + b2). One wave per row; 4 edge
// slots x 16 classes per lane; (j,w) register-cached + shfl broadcast.
// ---------------------------------------------------------------------------
__global__ __launch_bounds__(256) void kC(const float* __restrict__ hw,
                                          const int* __restrict__ rowcnt,
                                          const int* __restrict__ cols,
                                          const float* __restrict__ dinv,
                                          const float* __restrict__ b2,
                                          float* __restrict__ out) {
  int lane = threadIdx.x & 63;
  int wid = threadIdx.x >> 6;
  int row = blockIdx.x * 4 + wid;
  int cnt = rowcnt[row];
  const int* crow = cols + (size_t)row * CAP;
  int jA = 0; float wA = 0.0f;
  if (lane < cnt) { jA = crow[lane]; wA = dinv[jA]; }
  int jB = 0; float wB = 0.0f;
  if (lane + 64 < cnt) { jB = crow[lane + 64]; wB = dinv[jB]; }
  int c = lane & 15, slot = lane >> 4;
  float acc = 0.0f;
  for (int e0 = 0; e0 < cnt; e0 += 4) {
    int e = e0 + slot;
    int   j1 = __shfl(jA, e & 63);
    float w1 = __shfl(wA, e & 63);
    int   j2 = __shfl(jB, (e - 64) & 63);
    float w2 = __shfl(wB, (e - 64) & 63);
    int   j = (e < 64) ? j1 : j2;
    float w = (e < 64) ? w1 : w2;
    if (e < cnt) acc = fmaf(w, hw[(size_t)j * NCLASS + c], acc);
  }
  acc += __shfl_xor(acc, 16);
  acc += __shfl_xor(acc, 32);
  float di = dinv[row];
  float self = hw[(size_t)row * NCLASS + c];
  float v = fmaf(di, acc, fmaf(di * di, self, b2[c]));
  float m = v;
#pragma unroll
  for (int o = 8; o >= 1; o >>= 1) m = fmaxf(m, __shfl_xor(m, o, 16));
  float ex = __expf(v - m);
  float s = ex;
#pragma unroll
  for (int o = 8; o >= 1; o >>= 1) s += __shfl_xor(s, o, 16);
  if (slot == 0) out[(size_t)row * NCLASS + c] = v - m - logf(s);
}

// ---------------------------------------------------------------------------

extern "C" void kernel_launch(void* const* d_in, const int* in_sizes, int n_in,
                              void* d_out, int out_size, void* d_ws, size_t ws_size,
                              hipStream_t stream) {
  const float* x   = (const float*)d_in[0];
  const float* adj = (const float*)d_in[1];
  const float* W1  = (const float*)d_in[2];
  const float* b1  = (const float*)d_in[3];
  const float* W2  = (const float*)d_in[4];
  const float* b2  = (const float*)d_in[5];
  float* out = (float*)d_out;

  char* ws = (char*)d_ws;
  float* dinv = (float*)(ws);                      // 32 KB
  int*   rowc = (int*)(ws + 32768);                // 32 KB
  int*   cols = (int*)(ws + 65536);                // 4 MB
  float* xw   = (float*)(ws + 65536 + 4194304);    // 4 MB
  float* hw   = (float*)(ws + 65536 + 8388608);    // 512 KB

  kA<<<K1_BLOCKS + K2_BLOCKS, 256, 0, stream>>>(adj, x, W1, rowc, cols, dinv, xw);
  kB<<<NN, 128, 0, stream>>>(xw, rowc, cols, dinv, b1, W2, hw);
  kC<<<NN / 4, 256, 0, stream>>>(hw, rowc, cols, dinv, b2, out);
}

// Round 12
// 495.581 us; speedup vs baseline: 1.0477x; 1.0477x over previous
//
#include <hip/hip_runtime.h>

#define NN 8192
#define NFEAT 512
#define NHID 128
#define NCLASS 16
#define CAP 128
#define K1_BLOCKS (NN / 4)    // 2048: one row per wave, 4 waves/block
#define K2_BLOCKS (NN / 4)    // 2048: 4 rows per block -> full occupancy

__device__ __forceinline__ int mbcnt64(unsigned long long m) {
  return __builtin_amdgcn_mbcnt_hi((unsigned int)(m >> 32),
         __builtin_amdgcn_mbcnt_lo((unsigned int)m, 0));
}

// ---------------------------------------------------------------------------
// k1: wave-per-row adjacency compaction (SEPARATE dispatch this round).
// No LDS, no atomics, no barriers: ballot mask -> slot = running wave-uniform
// base + popcount-of-lower-lanes; scattered 4B store. Row order arbitrary.
// ---------------------------------------------------------------------------
__global__ __launch_bounds__(256) void k1_build(const float* __restrict__ adj,
                                                int* __restrict__ rowcnt,
                                                int* __restrict__ cols,
                                                float* __restrict__ dinv) {
  int lane = threadIdx.x & 63;
  int row = blockIdx.x * 4 + (threadIdx.x >> 6);
  const float4* arow = (const float4*)(adj + (size_t)row * NN);
  int* crow = cols + (size_t)row * CAP;
  int wbase = 0;                      // wave-uniform running count (SGPR)
  for (int i = 0; i < 4; ++i) {       // 4 x 8KB sweeps of the 32KB row
    float4 v[8];
#pragma unroll
    for (int u = 0; u < 8; ++u)
      v[u] = arow[i * 512 + u * 64 + lane];   // 8 loads in flight
#pragma unroll
    for (int u = 0; u < 8; ++u) {
      int cbase = (i * 512 + u * 64 + lane) * 4;
#pragma unroll
      for (int e = 0; e < 4; ++e) {
        float ve = (e == 0) ? v[u].x : (e == 1) ? v[u].y
                 : (e == 2) ? v[u].z : v[u].w;
        unsigned long long m = __ballot(ve != 0.0f);
        if (ve != 0.0f) {
          int pos = wbase + mbcnt64(m);
          if (pos < CAP) crow[pos] = cbase + e;
        }
        wbase += __popcll(m);
      }
    }
  }
  if (lane == 0) {
    rowcnt[row] = min(wbase, CAP);
    dinv[row] = rsqrtf((float)wbase + 1.0f);
  }
}

// ---------------------------------------------------------------------------
// k2: xw = x @ W1. [8192,512]@[512,128] f32.
// 2048 blocks x 4 rows (8192 waves = full machine; no thin-occupancy phase).
// Thread: p = tid&127 (col), g = tid>>7 (row pair) -> 2 rows x 1 col.
// ---------------------------------------------------------------------------
__global__ __launch_bounds__(256) void k2_gemm1(const float* __restrict__ x,
                                                const float* __restrict__ W1,
                                                float* __restrict__ xw) {
  int p = threadIdx.x & 127;
  int g = threadIdx.x >> 7;                 // 0..1
  int rbase = blockIdx.x * 4 + g * 2;
  const float* xr0 = x + (size_t)rbase * NFEAT;
  float acc0 = 0.0f, acc1 = 0.0f;
  for (int k = 0; k < NFEAT; k += 4) {
    float4 xv0 = *(const float4*)(xr0 + k);
    float4 xv1 = *(const float4*)(xr0 + NFEAT + k);
    float w0 = W1[(size_t)(k + 0) * NHID + p];
    float w1 = W1[(size_t)(k + 1) * NHID + p];
    float w2 = W1[(size_t)(k + 2) * NHID + p];
    float w3 = W1[(size_t)(k + 3) * NHID + p];
    acc0 = fmaf(xv0.x, w0, acc0); acc1 = fmaf(xv1.x, w0, acc1);
    acc0 = fmaf(xv0.y, w1, acc0); acc1 = fmaf(xv1.y, w1, acc1);
    acc0 = fmaf(xv0.z, w2, acc0); acc1 = fmaf(xv1.z, w2, acc1);
    acc0 = fmaf(xv0.w, w3, acc0); acc1 = fmaf(xv1.w, w3, acc1);
  }
  xw[(size_t)rbase * NHID + p]          = acc0;
  xw[(size_t)(rbase + 1) * NHID + p]    = acc1;
}

// ---------------------------------------------------------------------------
// Kernel B (fused gc1+relu+gc2-matmul): h_row = relu(A_norm @ xw + b1) in LDS,
// then hw_row = h_row @ W2 via per-block partial reduction. Block = one row.
// ---------------------------------------------------------------------------
__global__ __launch_bounds__(128) void kB(const float* __restrict__ xw,
                                          const int* __restrict__ rowcnt,
                                          const int* __restrict__ cols,
                                          const float* __restrict__ dinv,
                                          const float* __restrict__ b1,
                                          const float* __restrict__ W2,
                                          float* __restrict__ hw) {
  __shared__ int   sj[CAP];
  __shared__ float sw[CAP];
  __shared__ float sh[NHID];
  __shared__ float part[128];
  int row = blockIdx.x;
  int c = threadIdx.x;
  int cnt = rowcnt[row];
  const int* crow = cols + (size_t)row * CAP;
  if (c < cnt) { int j = crow[c]; sj[c] = j; sw[c] = dinv[j]; }
  __syncthreads();
  float di = dinv[row];
  float acc = di * xw[(size_t)row * NHID + c];   // self-loop (I) term
  int e = 0;
  for (; e + 4 <= cnt; e += 4) {
    int j0 = sj[e], j1 = sj[e + 1], j2 = sj[e + 2], j3 = sj[e + 3];
    float w0 = sw[e], w1 = sw[e + 1], w2 = sw[e + 2], w3 = sw[e + 3];
    float v0 = xw[(size_t)j0 * NHID + c];
    float v1 = xw[(size_t)j1 * NHID + c];
    float v2 = xw[(size_t)j2 * NHID + c];
    float v3 = xw[(size_t)j3 * NHID + c];
    acc = fmaf(w0, v0, acc);
    acc = fmaf(w1, v1, acc);
    acc = fmaf(w2, v2, acc);
    acc = fmaf(w3, v3, acc);
  }
  for (; e < cnt; ++e) acc = fmaf(sw[e], xw[(size_t)sj[e] * NHID + c], acc);
  float h = fmaxf(fmaf(di, acc, b1[c]), 0.0f);
  sh[c] = h;
  __syncthreads();
  int cc = c & 15, seg = c >> 4;
  float pacc = 0.0f;
#pragma unroll
  for (int kk = 0; kk < 16; ++kk) {
    int k = seg * 16 + kk;
    pacc = fmaf(sh[k], W2[(size_t)k * NCLASS + cc], pacc);
  }
  part[c] = pacc;
  __syncthreads();
  if (c < 16) {
    float s = 0.0f;
#pragma unroll
    for (int sg = 0; sg < 8; ++sg) s += part[c + 16 * sg];
    hw[(size_t)row * NCLASS + c] = s;
  }
}

// ---------------------------------------------------------------------------
// Kernel C: out = log_softmax(A_norm @ hw + b2). One wave per row; 4 edge
// slots x 16 classes per lane; (j,w) register-cached + shfl broadcast.
// ---------------------------------------------------------------------------
__global__ __launch_bounds__(256) void kC(const float* __restrict__ hw,
                                          const int* __restrict__ rowcnt,
                                          const int* __restrict__ cols,
                                          const float* __restrict__ dinv,
                                          const float* __restrict__ b2,
                                          float* __restrict__ out) {
  int lane = threadIdx.x & 63;
  int wid = threadIdx.x >> 6;
  int row = blockIdx.x * 4 + wid;
  int cnt = rowcnt[row];
  const int* crow = cols + (size_t)row * CAP;
  int jA = 0; float wA = 0.0f;
  if (lane < cnt) { jA = crow[lane]; wA = dinv[jA]; }
  int jB = 0; float wB = 0.0f;
  if (lane + 64 < cnt) { jB = crow[lane + 64]; wB = dinv[jB]; }
  int c = lane & 15, slot = lane >> 4;
  float acc = 0.0f;
  for (int e0 = 0; e0 < cnt; e0 += 4) {
    int e = e0 + slot;
    int   j1 = __shfl(jA, e & 63);
    float w1 = __shfl(wA, e & 63);
    int   j2 = __shfl(jB, (e - 64) & 63);
    float w2 = __shfl(wB, (e - 64) & 63);
    int   j = (e < 64) ? j1 : j2;
    float w = (e < 64) ? w1 : w2;
    if (e < cnt) acc = fmaf(w, hw[(size_t)j * NCLASS + c], acc);
  }
  acc += __shfl_xor(acc, 16);
  acc += __shfl_xor(acc, 32);
  float di = dinv[row];
  float self = hw[(size_t)row * NCLASS + c];
  float v = fmaf(di, acc, fmaf(di * di, self, b2[c]));
  float m = v;
#pragma unroll
  for (int o = 8; o >= 1; o >>= 1) m = fmaxf(m, __shfl_xor(m, o, 16));
  float ex = __expf(v - m);
  float s = ex;
#pragma unroll
  for (int o = 8; o >= 1; o >>= 1) s += __shfl_xor(s, o, 16);
  if (slot == 0) out[(size_t)row * NCLASS + c] = v - m - logf(s);
}

// ---------------------------------------------------------------------------

extern "C" void kernel_launch(void* const* d_in, const int* in_sizes, int n_in,
                              void* d_out, int out_size, void* d_ws, size_t ws_size,
                              hipStream_t stream) {
  const float* x   = (const float*)d_in[0];
  const float* adj = (const float*)d_in[1];
  const float* W1  = (const float*)d_in[2];
  const float* b1  = (const float*)d_in[3];
  const float* W2  = (const float*)d_in[4];
  const float* b2  = (const float*)d_in[5];
  float* out = (float*)d_out;

  char* ws = (char*)d_ws;
  float* dinv = (float*)(ws);                      // 32 KB
  int*   rowc = (int*)(ws + 32768);                // 32 KB
  int*   cols = (int*)(ws + 65536);                // 4 MB
  float* xw   = (float*)(ws + 65536 + 4194304);    // 4 MB
  float* hw   = (float*)(ws + 65536 + 8388608);    // 512 KB

  k1_build<<<K1_BLOCKS, 256, 0, stream>>>(adj, rowc, cols, dinv);
  k2_gemm1<<<K2_BLOCKS, 256, 0, stream>>>(x, W1, xw);
  kB<<<NN, 128, 0, stream>>>(xw, rowc, cols, dinv, b1, W2, hw);
  kC<<<NN / 4, 256, 0, stream>>>(hw, rowc, cols, dinv, b2, out);
}

// Round 13
// 462.449 us; speedup vs baseline: 1.1228x; 1.0716x over previous
//
#include <hip/hip_runtime.h>

#define NN 8192
#define NFEAT 512
#define NHID 128
#define NCLASS 16
#define CAP 128

// ---------------------------------------------------------------------------
// k1: block-per-row adjacency compaction (R2 structure, best measured).
// ONE change vs R2: all 8 float4 loads issued up-front (more MLP), scan after.
// ---------------------------------------------------------------------------
__global__ __launch_bounds__(256) void k1_build(const float* __restrict__ adj,
                                                int* __restrict__ rowcnt,
                                                int* __restrict__ cols,
                                                float* __restrict__ dinv) {
  int row = blockIdx.x;
  __shared__ int cnt;
  if (threadIdx.x == 0) cnt = 0;
  __syncthreads();
  const float4* arow = (const float4*)(adj + (size_t)row * NN);
  int* crow = cols + (size_t)row * CAP;
  float4 v[8];
#pragma unroll
  for (int u = 0; u < 8; ++u)
    v[u] = arow[threadIdx.x + 256 * u];          // 8 x 4KB loads in flight
#pragma unroll
  for (int u = 0; u < 8; ++u) {
    int j0 = (threadIdx.x + 256 * u) * 4;
    if (v[u].x != 0.0f) { int s = atomicAdd(&cnt, 1); if (s < CAP) crow[s] = j0; }
    if (v[u].y != 0.0f) { int s = atomicAdd(&cnt, 1); if (s < CAP) crow[s] = j0 + 1; }
    if (v[u].z != 0.0f) { int s = atomicAdd(&cnt, 1); if (s < CAP) crow[s] = j0 + 2; }
    if (v[u].w != 0.0f) { int s = atomicAdd(&cnt, 1); if (s < CAP) crow[s] = j0 + 3; }
  }
  __syncthreads();
  if (threadIdx.x == 0) {
    rowcnt[row] = min(cnt, CAP);
    dinv[row] = rsqrtf((float)cnt + 1.0f);
  }
}

// ---------------------------------------------------------------------------
// k2: xw = x @ W1. [8192,512]@[512,128] f32. R2 form: 512 blocks x 16 rows,
// thread (p = tid&127, g = tid>>7) computes 8 rows x 1 col.
// ---------------------------------------------------------------------------
__global__ __launch_bounds__(256) void k2_gemm1(const float* __restrict__ x,
                                                const float* __restrict__ W1,
                                                float* __restrict__ xw) {
  int p = threadIdx.x & 127;
  int g = threadIdx.x >> 7;                     // 0..1
  int rbase = blockIdx.x * 16 + g * 8;
  const float* xr0 = x + (size_t)rbase * NFEAT;
  float acc[8] = {};
  for (int k = 0; k < NFEAT; k += 4) {
    float4 xv[8];
#pragma unroll
    for (int r = 0; r < 8; ++r)
      xv[r] = *(const float4*)(xr0 + (size_t)r * NFEAT + k);
#pragma unroll
    for (int t = 0; t < 4; ++t) {
      float w = W1[(size_t)(k + t) * NHID + p];
#pragma unroll
      for (int r = 0; r < 8; ++r) {
        float xe = (t == 0) ? xv[r].x : (t == 1) ? xv[r].y
                 : (t == 2) ? xv[r].z : xv[r].w;
        acc[r] = fmaf(xe, w, acc[r]);
      }
    }
  }
#pragma unroll
  for (int r = 0; r < 8; ++r)
    xw[(size_t)(rbase + r) * NHID + p] = acc[r];
}

// ---------------------------------------------------------------------------
// Kernel B (fused gc1+relu+gc2-matmul): h_row = relu(A_norm @ xw + b1) in LDS,
// then hw_row = h_row @ W2 via per-block partial reduction. Block = one row.
// ---------------------------------------------------------------------------
__global__ __launch_bounds__(128) void kB(const float* __restrict__ xw,
                                          const int* __restrict__ rowcnt,
                                          const int* __restrict__ cols,
                                          const float* __restrict__ dinv,
                                          const float* __restrict__ b1,
                                          const float* __restrict__ W2,
                                          float* __restrict__ hw) {
  __shared__ int   sj[CAP];
  __shared__ float sw[CAP];
  __shared__ float sh[NHID];
  __shared__ float part[128];
  int row = blockIdx.x;
  int c = threadIdx.x;
  int cnt = rowcnt[row];
  const int* crow = cols + (size_t)row * CAP;
  if (c < cnt) { int j = crow[c]; sj[c] = j; sw[c] = dinv[j]; }
  __syncthreads();
  float di = dinv[row];
  float acc = di * xw[(size_t)row * NHID + c];   // self-loop (I) term
  int e = 0;
  for (; e + 4 <= cnt; e += 4) {
    int j0 = sj[e], j1 = sj[e + 1], j2 = sj[e + 2], j3 = sj[e + 3];
    float w0 = sw[e], w1 = sw[e + 1], w2 = sw[e + 2], w3 = sw[e + 3];
    float v0 = xw[(size_t)j0 * NHID + c];
    float v1 = xw[(size_t)j1 * NHID + c];
    float v2 = xw[(size_t)j2 * NHID + c];
    float v3 = xw[(size_t)j3 * NHID + c];
    acc = fmaf(w0, v0, acc);
    acc = fmaf(w1, v1, acc);
    acc = fmaf(w2, v2, acc);
    acc = fmaf(w3, v3, acc);
  }
  for (; e < cnt; ++e) acc = fmaf(sw[e], xw[(size_t)sj[e] * NHID + c], acc);
  float h = fmaxf(fmaf(di, acc, b1[c]), 0.0f);
  sh[c] = h;
  __syncthreads();
  int cc = c & 15, seg = c >> 4;
  float pacc = 0.0f;
#pragma unroll
  for (int kk = 0; kk < 16; ++kk) {
    int k = seg * 16 + kk;
    pacc = fmaf(sh[k], W2[(size_t)k * NCLASS + cc], pacc);
  }
  part[c] = pacc;
  __syncthreads();
  if (c < 16) {
    float s = 0.0f;
#pragma unroll
    for (int sg = 0; sg < 8; ++sg) s += part[c + 16 * sg];
    hw[(size_t)row * NCLASS + c] = s;
  }
}

// ---------------------------------------------------------------------------
// Kernel C: out = log_softmax(A_norm @ hw + b2). One wave per row; 4 edge
// slots x 16 classes per lane; (j,w) register-cached + shfl broadcast.
// ---------------------------------------------------------------------------
__global__ __launch_bounds__(256) void kC(const float* __restrict__ hw,
                                          const int* __restrict__ rowcnt,
                                          const int* __restrict__ cols,
                                          const float* __restrict__ dinv,
                                          const float* __restrict__ b2,
                                          float* __restrict__ out) {
  int lane = threadIdx.x & 63;
  int wid = threadIdx.x >> 6;
  int row = blockIdx.x * 4 + wid;
  int cnt = rowcnt[row];
  const int* crow = cols + (size_t)row * CAP;
  int jA = 0; float wA = 0.0f;
  if (lane < cnt) { jA = crow[lane]; wA = dinv[jA]; }
  int jB = 0; float wB = 0.0f;
  if (lane + 64 < cnt) { jB = crow[lane + 64]; wB = dinv[jB]; }
  int c = lane & 15, slot = lane >> 4;
  float acc = 0.0f;
  for (int e0 = 0; e0 < cnt; e0 += 4) {
    int e = e0 + slot;
    int   j1 = __shfl(jA, e & 63);
    float w1 = __shfl(wA, e & 63);
    int   j2 = __shfl(jB, (e - 64) & 63);
    float w2 = __shfl(wB, (e - 64) & 63);
    int   j = (e < 64) ? j1 : j2;
    float w = (e < 64) ? w1 : w2;
    if (e < cnt) acc = fmaf(w, hw[(size_t)j * NCLASS + c], acc);
  }
  acc += __shfl_xor(acc, 16);
  acc += __shfl_xor(acc, 32);
  float di = dinv[row];
  float self = hw[(size_t)row * NCLASS + c];
  float v = fmaf(di, acc, fmaf(di * di, self, b2[c]));
  float m = v;
#pragma unroll
  for (int o = 8; o >= 1; o >>= 1) m = fmaxf(m, __shfl_xor(m, o, 16));
  float ex = __expf(v - m);
  float s = ex;
#pragma unroll
  for (int o = 8; o >= 1; o >>= 1) s += __shfl_xor(s, o, 16);
  if (slot == 0) out[(size_t)row * NCLASS + c] = v - m - logf(s);
}

// ---------------------------------------------------------------------------

extern "C" void kernel_launch(void* const* d_in, const int* in_sizes, int n_in,
                              void* d_out, int out_size, void* d_ws, size_t ws_size,
                              hipStream_t stream) {
  const float* x   = (const float*)d_in[0];
  const float* adj = (const float*)d_in[1];
  const float* W1  = (const float*)d_in[2];
  const float* b1  = (const float*)d_in[3];
  const float* W2  = (const float*)d_in[4];
  const float* b2  = (const float*)d_in[5];
  float* out = (float*)d_out;

  char* ws = (char*)d_ws;
  float* dinv = (float*)(ws);                      // 32 KB
  int*   rowc = (int*)(ws + 32768);                // 32 KB
  int*   cols = (int*)(ws + 65536);                // 4 MB
  float* xw   = (float*)(ws + 65536 + 4194304);    // 4 MB
  float* hw   = (float*)(ws + 65536 + 8388608);    // 512 KB

  k1_build<<<NN, 256, 0, stream>>>(adj, rowc, cols, dinv);
  k2_gemm1<<<NN / 16, 256, 0, stream>>>(x, W1, xw);
  kB<<<NN, 128, 0, stream>>>(xw, rowc, cols, dinv, b1, W2, hw);
  kC<<<NN / 4, 256, 0, stream>>>(hw, rowc, cols, dinv, b2, out);
}

// Round 14
// 449.523 us; speedup vs baseline: 1.1551x; 1.0288x over previous
//
#include <hip/hip_runtime.h>

#define NN 8192
#define NFEAT 512
#define NHID 128
#define NCLASS 16
#define CAP 128
#define K2B (NN / 16)   // 512 GEMM blocks, dispatched FIRST

// ---------------------------------------------------------------------------
// kA: merged k2 (GEMM, blocks [0,K2B)) + k1 (adj compaction, blocks [K2B,..)).
// GEMM first: its 512 blocks start while the 8192 k1 blocks flood in behind,
// so the GEMM runs fully overlapped with k1's HBM phase and there is no
// thin-occupancy tail (R10's merge had GEMM last -> +24 us tail).
// k1 body = R13's measured-at-floor version (burst loads + LDS atomic).
// ---------------------------------------------------------------------------
__global__ __launch_bounds__(256) void kA(const float* __restrict__ adj,
                                          const float* __restrict__ x,
                                          const float* __restrict__ W1,
                                          int* __restrict__ rowcnt,
                                          int* __restrict__ cols,
                                          float* __restrict__ dinv,
                                          float* __restrict__ xw) {
  if (blockIdx.x < K2B) {
    // ---- k2: xw = x @ W1 (16 rows/block, 8 rows x 1 col per thread) ----
    int p = threadIdx.x & 127;
    int g = threadIdx.x >> 7;                 // 0..1
    int rbase = blockIdx.x * 16 + g * 8;
    const float* xr0 = x + (size_t)rbase * NFEAT;
    float acc[8] = {};
    for (int k = 0; k < NFEAT; k += 4) {
      float4 xv[8];
#pragma unroll
      for (int r = 0; r < 8; ++r)
        xv[r] = *(const float4*)(xr0 + (size_t)r * NFEAT + k);
#pragma unroll
      for (int t = 0; t < 4; ++t) {
        float w = W1[(size_t)(k + t) * NHID + p];
#pragma unroll
        for (int r = 0; r < 8; ++r) {
          float xe = (t == 0) ? xv[r].x : (t == 1) ? xv[r].y
                   : (t == 2) ? xv[r].z : xv[r].w;
          acc[r] = fmaf(xe, w, acc[r]);
        }
      }
    }
#pragma unroll
    for (int r = 0; r < 8; ++r)
      xw[(size_t)(rbase + r) * NHID + p] = acc[r];
  } else {
    // ---- k1: block-per-row adjacency compaction ----
    int row = blockIdx.x - K2B;
    __shared__ int cnt;
    if (threadIdx.x == 0) cnt = 0;
    __syncthreads();
    const float4* arow = (const float4*)(adj + (size_t)row * NN);
    int* crow = cols + (size_t)row * CAP;
    float4 v[8];
#pragma unroll
    for (int u = 0; u < 8; ++u)
      v[u] = arow[threadIdx.x + 256 * u];        // 8 x 4KB loads in flight
#pragma unroll
    for (int u = 0; u < 8; ++u) {
      int j0 = (threadIdx.x + 256 * u) * 4;
      if (v[u].x != 0.0f) { int s = atomicAdd(&cnt, 1); if (s < CAP) crow[s] = j0; }
      if (v[u].y != 0.0f) { int s = atomicAdd(&cnt, 1); if (s < CAP) crow[s] = j0 + 1; }
      if (v[u].z != 0.0f) { int s = atomicAdd(&cnt, 1); if (s < CAP) crow[s] = j0 + 2; }
      if (v[u].w != 0.0f) { int s = atomicAdd(&cnt, 1); if (s < CAP) crow[s] = j0 + 3; }
    }
    __syncthreads();
    if (threadIdx.x == 0) {
      rowcnt[row] = min(cnt, CAP);
      dinv[row] = rsqrtf((float)cnt + 1.0f);
    }
  }
}

// ---------------------------------------------------------------------------
// Kernel B (fused gc1+relu+gc2-matmul): h_row = relu(A_norm @ xw + b1) in LDS,
// then hw_row = h_row @ W2 via per-block partial reduction. Block = one row.
// ---------------------------------------------------------------------------
__global__ __launch_bounds__(128) void kB(const float* __restrict__ xw,
                                          const int* __restrict__ rowcnt,
                                          const int* __restrict__ cols,
                                          const float* __restrict__ dinv,
                                          const float* __restrict__ b1,
                                          const float* __restrict__ W2,
                                          float* __restrict__ hw) {
  __shared__ int   sj[CAP];
  __shared__ float sw[CAP];
  __shared__ float sh[NHID];
  __shared__ float part[128];
  int row = blockIdx.x;
  int c = threadIdx.x;
  int cnt = rowcnt[row];
  const int* crow = cols + (size_t)row * CAP;
  if (c < cnt) { int j = crow[c]; sj[c] = j; sw[c] = dinv[j]; }
  __syncthreads();
  float di = dinv[row];
  float acc = di * xw[(size_t)row * NHID + c];   // self-loop (I) term
  int e = 0;
  for (; e + 4 <= cnt; e += 4) {
    int j0 = sj[e], j1 = sj[e + 1], j2 = sj[e + 2], j3 = sj[e + 3];
    float w0 = sw[e], w1 = sw[e + 1], w2 = sw[e + 2], w3 = sw[e + 3];
    float v0 = xw[(size_t)j0 * NHID + c];
    float v1 = xw[(size_t)j1 * NHID + c];
    float v2 = xw[(size_t)j2 * NHID + c];
    float v3 = xw[(size_t)j3 * NHID + c];
    acc = fmaf(w0, v0, acc);
    acc = fmaf(w1, v1, acc);
    acc = fmaf(w2, v2, acc);
    acc = fmaf(w3, v3, acc);
  }
  for (; e < cnt; ++e) acc = fmaf(sw[e], xw[(size_t)sj[e] * NHID + c], acc);
  float h = fmaxf(fmaf(di, acc, b1[c]), 0.0f);
  sh[c] = h;
  __syncthreads();
  int cc = c & 15, seg = c >> 4;
  float pacc = 0.0f;
#pragma unroll
  for (int kk = 0; kk < 16; ++kk) {
    int k = seg * 16 + kk;
    pacc = fmaf(sh[k], W2[(size_t)k * NCLASS + cc], pacc);
  }
  part[c] = pacc;
  __syncthreads();
  if (c < 16) {
    float s = 0.0f;
#pragma unroll
    for (int sg = 0; sg < 8; ++sg) s += part[c + 16 * sg];
    hw[(size_t)row * NCLASS + c] = s;
  }
}

// ---------------------------------------------------------------------------
// Kernel C: out = log_softmax(A_norm @ hw + b2). One wave per row; 4 edge
// slots x 16 classes per lane; (j,w) register-cached + shfl broadcast.
// ---------------------------------------------------------------------------
__global__ __launch_bounds__(256) void kC(const float* __restrict__ hw,
                                          const int* __restrict__ rowcnt,
                                          const int* __restrict__ cols,
                                          const float* __restrict__ dinv,
                                          const float* __restrict__ b2,
                                          float* __restrict__ out) {
  int lane = threadIdx.x & 63;
  int wid = threadIdx.x >> 6;
  int row = blockIdx.x * 4 + wid;
  int cnt = rowcnt[row];
  const int* crow = cols + (size_t)row * CAP;
  int jA = 0; float wA = 0.0f;
  if (lane < cnt) { jA = crow[lane]; wA = dinv[jA]; }
  int jB = 0; float wB = 0.0f;
  if (lane + 64 < cnt) { jB = crow[lane + 64]; wB = dinv[jB]; }
  int c = lane & 15, slot = lane >> 4;
  float acc = 0.0f;
  for (int e0 = 0; e0 < cnt; e0 += 4) {
    int e = e0 + slot;
    int   j1 = __shfl(jA, e & 63);
    float w1 = __shfl(wA, e & 63);
    int   j2 = __shfl(jB, (e - 64) & 63);
    float w2 = __shfl(wB, (e - 64) & 63);
    int   j = (e < 64) ? j1 : j2;
    float w = (e < 64) ? w1 : w2;
    if (e < cnt) acc = fmaf(w, hw[(size_t)j * NCLASS + c], acc);
  }
  acc += __shfl_xor(acc, 16);
  acc += __shfl_xor(acc, 32);
  float di = dinv[row];
  float self = hw[(size_t)row * NCLASS + c];
  float v = fmaf(di, acc, fmaf(di * di, self, b2[c]));
  float m = v;
#pragma unroll
  for (int o = 8; o >= 1; o >>= 1) m = fmaxf(m, __shfl_xor(m, o, 16));
  float ex = __expf(v - m);
  float s = ex;
#pragma unroll
  for (int o = 8; o >= 1; o >>= 1) s += __shfl_xor(s, o, 16);
  if (slot == 0) out[(size_t)row * NCLASS + c] = v - m - logf(s);
}

// ---------------------------------------------------------------------------

extern "C" void kernel_launch(void* const* d_in, const int* in_sizes, int n_in,
                              void* d_out, int out_size, void* d_ws, size_t ws_size,
                              hipStream_t stream) {
  const float* x   = (const float*)d_in[0];
  const float* adj = (const float*)d_in[1];
  const float* W1  = (const float*)d_in[2];
  const float* b1  = (const float*)d_in[3];
  const float* W2  = (const float*)d_in[4];
  const float* b2  = (const float*)d_in[5];
  float* out = (float*)d_out;

  char* ws = (char*)d_ws;
  float* dinv = (float*)(ws);                      // 32 KB
  int*   rowc = (int*)(ws + 32768);                // 32 KB
  int*   cols = (int*)(ws + 65536);                // 4 MB
  float* xw   = (float*)(ws + 65536 + 4194304);    // 4 MB
  float* hw   = (float*)(ws + 65536 + 8388608);    // 512 KB

  kA<<<K2B + NN, 256, 0, stream>>>(adj, x, W1, rowc, cols, dinv, xw);
  kB<<<NN, 128, 0, stream>>>(xw, rowc, cols, dinv, b1, W2, hw);
  kC<<<NN / 4, 256, 0, stream>>>(hw, rowc, cols, dinv, b2, out);
}

// Round 15
// 447.002 us; speedup vs baseline: 1.1616x; 1.0056x over previous
//
#include <hip/hip_runtime.h>

#define NN 8192
#define NFEAT 512
#define NHID 128
#define NCLASS 16
#define CAP 128
#define K2B (NN / 16)   // 512 GEMM blocks, dispatched FIRST
#define K1B (NN / 2)    // 4096 scan blocks, 2 rows each

// ---------------------------------------------------------------------------
// kA: merged k2 (GEMM, blocks [0,K2B)) + k1 (adj scan, blocks [K2B, +K1B)).
// k1 change vs R14: each block owns TWO rows and issues all 16 float4 loads
// (64 KB) before scanning either row -> 3.3x more bytes in flight per CU.
// Two LDS counters so both scans run back-to-back without a barrier.
// ---------------------------------------------------------------------------
__global__ __launch_bounds__(256) void kA(const float* __restrict__ adj,
                                          const float* __restrict__ x,
                                          const float* __restrict__ W1,
                                          int* __restrict__ rowcnt,
                                          int* __restrict__ cols,
                                          float* __restrict__ dinv,
                                          float* __restrict__ xw) {
  if (blockIdx.x < K2B) {
    // ---- k2: xw = x @ W1 (16 rows/block, 8 rows x 1 col per thread) ----
    int p = threadIdx.x & 127;
    int g = threadIdx.x >> 7;                 // 0..1
    int rbase = blockIdx.x * 16 + g * 8;
    const float* xr0 = x + (size_t)rbase * NFEAT;
    float acc[8] = {};
    for (int k = 0; k < NFEAT; k += 4) {
      float4 xv[8];
#pragma unroll
      for (int r = 0; r < 8; ++r)
        xv[r] = *(const float4*)(xr0 + (size_t)r * NFEAT + k);
#pragma unroll
      for (int t = 0; t < 4; ++t) {
        float w = W1[(size_t)(k + t) * NHID + p];
#pragma unroll
        for (int r = 0; r < 8; ++r) {
          float xe = (t == 0) ? xv[r].x : (t == 1) ? xv[r].y
                   : (t == 2) ? xv[r].z : xv[r].w;
          acc[r] = fmaf(xe, w, acc[r]);
        }
      }
    }
#pragma unroll
    for (int r = 0; r < 8; ++r)
      xw[(size_t)(rbase + r) * NHID + p] = acc[r];
  } else {
    // ---- k1: 2-row adjacency compaction with 64 KB burst ----
    int row0 = (blockIdx.x - K2B) * 2;
    __shared__ int cnt0, cnt1;
    if (threadIdx.x == 0) { cnt0 = 0; cnt1 = 0; }
    __syncthreads();
    const float4* a0 = (const float4*)(adj + (size_t)row0 * NN);
    const float4* a1 = (const float4*)(adj + (size_t)(row0 + 1) * NN);
    int* crow0 = cols + (size_t)row0 * CAP;
    int* crow1 = cols + (size_t)(row0 + 1) * CAP;
    float4 v0[8], v1[8];
#pragma unroll
    for (int u = 0; u < 8; ++u) v0[u] = a0[threadIdx.x + 256 * u];
#pragma unroll
    for (int u = 0; u < 8; ++u) v1[u] = a1[threadIdx.x + 256 * u];
    // scan row0 (waits only on v0's loads; v1's stay in flight)
#pragma unroll
    for (int u = 0; u < 8; ++u) {
      int j0 = (threadIdx.x + 256 * u) * 4;
      if (v0[u].x != 0.0f) { int s = atomicAdd(&cnt0, 1); if (s < CAP) crow0[s] = j0; }
      if (v0[u].y != 0.0f) { int s = atomicAdd(&cnt0, 1); if (s < CAP) crow0[s] = j0 + 1; }
      if (v0[u].z != 0.0f) { int s = atomicAdd(&cnt0, 1); if (s < CAP) crow0[s] = j0 + 2; }
      if (v0[u].w != 0.0f) { int s = atomicAdd(&cnt0, 1); if (s < CAP) crow0[s] = j0 + 3; }
    }
    // scan row1
#pragma unroll
    for (int u = 0; u < 8; ++u) {
      int j0 = (threadIdx.x + 256 * u) * 4;
      if (v1[u].x != 0.0f) { int s = atomicAdd(&cnt1, 1); if (s < CAP) crow1[s] = j0; }
      if (v1[u].y != 0.0f) { int s = atomicAdd(&cnt1, 1); if (s < CAP) crow1[s] = j0 + 1; }
      if (v1[u].z != 0.0f) { int s = atomicAdd(&cnt1, 1); if (s < CAP) crow1[s] = j0 + 2; }
      if (v1[u].w != 0.0f) { int s = atomicAdd(&cnt1, 1); if (s < CAP) crow1[s] = j0 + 3; }
    }
    __syncthreads();
    if (threadIdx.x == 0) {
      rowcnt[row0] = min(cnt0, CAP);
      dinv[row0] = rsqrtf((float)cnt0 + 1.0f);
      rowcnt[row0 + 1] = min(cnt1, CAP);
      dinv[row0 + 1] = rsqrtf((float)cnt1 + 1.0f);
    }
  }
}

// ---------------------------------------------------------------------------
// Kernel B (fused gc1+relu+gc2-matmul): h_row = relu(A_norm @ xw + b1) in LDS,
// then hw_row = h_row @ W2 via per-block partial reduction. Block = one row.
// ---------------------------------------------------------------------------
__global__ __launch_bounds__(128) void kB(const float* __restrict__ xw,
                                          const int* __restrict__ rowcnt,
                                          const int* __restrict__ cols,
                                          const float* __restrict__ dinv,
                                          const float* __restrict__ b1,
                                          const float* __restrict__ W2,
                                          float* __restrict__ hw) {
  __shared__ int   sj[CAP];
  __shared__ float sw[CAP];
  __shared__ float sh[NHID];
  __shared__ float part[128];
  int row = blockIdx.x;
  int c = threadIdx.x;
  int cnt = rowcnt[row];
  const int* crow = cols + (size_t)row * CAP;
  if (c < cnt) { int j = crow[c]; sj[c] = j; sw[c] = dinv[j]; }
  __syncthreads();
  float di = dinv[row];
  float acc = di * xw[(size_t)row * NHID + c];   // self-loop (I) term
  int e = 0;
  for (; e + 4 <= cnt; e += 4) {
    int j0 = sj[e], j1 = sj[e + 1], j2 = sj[e + 2], j3 = sj[e + 3];
    float w0 = sw[e], w1 = sw[e + 1], w2 = sw[e + 2], w3 = sw[e + 3];
    float v0 = xw[(size_t)j0 * NHID + c];
    float v1 = xw[(size_t)j1 * NHID + c];
    float v2 = xw[(size_t)j2 * NHID + c];
    float v3 = xw[(size_t)j3 * NHID + c];
    acc = fmaf(w0, v0, acc);
    acc = fmaf(w1, v1, acc);
    acc = fmaf(w2, v2, acc);
    acc = fmaf(w3, v3, acc);
  }
  for (; e < cnt; ++e) acc = fmaf(sw[e], xw[(size_t)sj[e] * NHID + c], acc);
  float h = fmaxf(fmaf(di, acc, b1[c]), 0.0f);
  sh[c] = h;
  __syncthreads();
  int cc = c & 15, seg = c >> 4;
  float pacc = 0.0f;
#pragma unroll
  for (int kk = 0; kk < 16; ++kk) {
    int k = seg * 16 + kk;
    pacc = fmaf(sh[k], W2[(size_t)k * NCLASS + cc], pacc);
  }
  part[c] = pacc;
  __syncthreads();
  if (c < 16) {
    float s = 0.0f;
#pragma unroll
    for (int sg = 0; sg < 8; ++sg) s += part[c + 16 * sg];
    hw[(size_t)row * NCLASS + c] = s;
  }
}

// ---------------------------------------------------------------------------
// Kernel C: out = log_softmax(A_norm @ hw + b2). One wave per row; 4 edge
// slots x 16 classes per lane; (j,w) register-cached + shfl broadcast.
// ---------------------------------------------------------------------------
__global__ __launch_bounds__(256) void kC(const float* __restrict__ hw,
                                          const int* __restrict__ rowcnt,
                                          const int* __restrict__ cols,
                                          const float* __restrict__ dinv,
                                          const float* __restrict__ b2,
                                          float* __restrict__ out) {
  int lane = threadIdx.x & 63;
  int wid = threadIdx.x >> 6;
  int row = blockIdx.x * 4 + wid;
  int cnt = rowcnt[row];
  const int* crow = cols + (size_t)row * CAP;
  int jA = 0; float wA = 0.0f;
  if (lane < cnt) { jA = crow[lane]; wA = dinv[jA]; }
  int jB = 0; float wB = 0.0f;
  if (lane + 64 < cnt) { jB = crow[lane + 64]; wB = dinv[jB]; }
  int c = lane & 15, slot = lane >> 4;
  float acc = 0.0f;
  for (int e0 = 0; e0 < cnt; e0 += 4) {
    int e = e0 + slot;
    int   j1 = __shfl(jA, e & 63);
    float w1 = __shfl(wA, e & 63);
    int   j2 = __shfl(jB, (e - 64) & 63);
    float w2 = __shfl(wB, (e - 64) & 63);
    int   j = (e < 64) ? j1 : j2;
    float w = (e < 64) ? w1 : w2;
    if (e < cnt) acc = fmaf(w, hw[(size_t)j * NCLASS + c], acc);
  }
  acc += __shfl_xor(acc, 16);
  acc += __shfl_xor(acc, 32);
  float di = dinv[row];
  float self = hw[(size_t)row * NCLASS + c];
  float v = fmaf(di, acc, fmaf(di * di, self, b2[c]));
  float m = v;
#pragma unroll
  for (int o = 8; o >= 1; o >>= 1) m = fmaxf(m, __shfl_xor(m, o, 16));
  float ex = __expf(v - m);
  float s = ex;
#pragma unroll
  for (int o = 8; o >= 1; o >>= 1) s += __shfl_xor(s, o, 16);
  if (slot == 0) out[(size_t)row * NCLASS + c] = v - m - logf(s);
}

// ---------------------------------------------------------------------------

extern "C" void kernel_launch(void* const* d_in, const int* in_sizes, int n_in,
                              void* d_out, int out_size, void* d_ws, size_t ws_size,
                              hipStream_t stream) {
  const float* x   = (const float*)d_in[0];
  const float* adj = (const float*)d_in[1];
  const float* W1  = (const float*)d_in[2];
  const float* b1  = (const float*)d_in[3];
  const float* W2  = (const float*)d_in[4];
  const float* b2  = (const float*)d_in[5];
  float* out = (float*)d_out;

  char* ws = (char*)d_ws;
  float* dinv = (float*)(ws);                      // 32 KB
  int*   rowc = (int*)(ws + 32768);                // 32 KB
  int*   cols = (int*)(ws + 65536);                // 4 MB
  float* xw   = (float*)(ws + 65536 + 4194304);    // 4 MB
  float* hw   = (float*)(ws + 65536 + 8388608);    // 512 KB

  kA<<<K2B + K1B, 256, 0, stream>>>(adj, x, W1, rowc, cols, dinv, xw);
  kB<<<NN, 128, 0, stream>>>(xw, rowc, cols, dinv, b1, W2, hw);
  kC<<<NN / 4, 256, 0, stream>>>(hw, rowc, cols, dinv, b2, out);
}

// Round 16
// 442.852 us; speedup vs baseline: 1.1725x; 1.0094x over previous
//
#include <hip/hip_runtime.h>

#define NN 8192
#define NFEAT 512
#define NHID 128
#define NCLASS 16
#define CAP 128
#define K2B (NN / 16)   // 512 GEMM blocks, dispatched FIRST
#define K1B (NN / 4)    // 2048 scan blocks: wave-per-row, 4 waves/block

__device__ __forceinline__ int mbcnt64(unsigned long long m) {
  return __builtin_amdgcn_mbcnt_hi((unsigned int)(m >> 32),
         __builtin_amdgcn_mbcnt_lo((unsigned int)m, 0));
}

// ---------------------------------------------------------------------------
// kA: merged k2 (GEMM, blocks [0,K2B)) + k1 (adj scan, blocks [K2B,+K1B)).
// k1 scan rework (the ONE variable this round): two-level zero-skip.
//   L1: integer-OR the 4 words of each uint4 (adj is bit-exact 0x0 / 1.0f);
//       wave ballot on the OR -> s_cbranch skips the whole chunk-round when
//       no lane has a nonzero (~36% of rounds).
//   L2: per-word ballot; ~77% of words skip via scalar branch; only truly
//       nonzero words run the mbcnt/popcount compaction store.
// No LDS, no atomics, no barriers in the scan. Row order arbitrary (consumer
// only sums neighbors).
// ---------------------------------------------------------------------------
__global__ __launch_bounds__(256) void kA(const float* __restrict__ adj,
                                          const float* __restrict__ x,
                                          const float* __restrict__ W1,
                                          int* __restrict__ rowcnt,
                                          int* __restrict__ cols,
                                          float* __restrict__ dinv,
                                          float* __restrict__ xw) {
  if (blockIdx.x < K2B) {
    // ---- k2: xw = x @ W1 (16 rows/block, 8 rows x 1 col per thread) ----
    int p = threadIdx.x & 127;
    int g = threadIdx.x >> 7;                 // 0..1
    int rbase = blockIdx.x * 16 + g * 8;
    const float* xr0 = x + (size_t)rbase * NFEAT;
    float acc[8] = {};
    for (int k = 0; k < NFEAT; k += 4) {
      float4 xv[8];
#pragma unroll
      for (int r = 0; r < 8; ++r)
        xv[r] = *(const float4*)(xr0 + (size_t)r * NFEAT + k);
#pragma unroll
      for (int t = 0; t < 4; ++t) {
        float w = W1[(size_t)(k + t) * NHID + p];
#pragma unroll
        for (int r = 0; r < 8; ++r) {
          float xe = (t == 0) ? xv[r].x : (t == 1) ? xv[r].y
                   : (t == 2) ? xv[r].z : xv[r].w;
          acc[r] = fmaf(xe, w, acc[r]);
        }
      }
    }
#pragma unroll
    for (int r = 0; r < 8; ++r)
      xw[(size_t)(rbase + r) * NHID + p] = acc[r];
  } else {
    // ---- k1: wave-per-row compaction with two-level zero-skip ----
    int lane = threadIdx.x & 63;
    int row = (blockIdx.x - K2B) * 4 + (threadIdx.x >> 6);
    const uint4* arow = (const uint4*)(adj + (size_t)row * NN);
    int* crow = cols + (size_t)row * CAP;
    int wbase = 0;                       // wave-uniform running count (SGPR)
    for (int i = 0; i < 4; ++i) {        // 4 x 8KB sweeps of the 32KB row
      uint4 v[8];
#pragma unroll
      for (int u = 0; u < 8; ++u)
        v[u] = arow[i * 512 + u * 64 + lane];   // 8 loads in flight
#pragma unroll
      for (int u = 0; u < 8; ++u) {
        unsigned o = v[u].x | v[u].y | v[u].z | v[u].w;
        unsigned long long m4 = __ballot(o != 0u);
        if (m4 == 0ull) continue;        // whole wave-round zero: ~36% skip
        int cbase = (i * 512 + u * 64 + lane) * 4;
#pragma unroll
        for (int e = 0; e < 4; ++e) {
          unsigned ve = (e == 0) ? v[u].x : (e == 1) ? v[u].y
                      : (e == 2) ? v[u].z : v[u].w;
          unsigned long long m = __ballot(ve != 0u);
          if (m != 0ull) {               // scalar skip: ~77% of words
            if (ve != 0u) {
              int pos = wbase + mbcnt64(m);
              if (pos < CAP) crow[pos] = cbase + e;
            }
            wbase += __popcll(m);
          }
        }
      }
    }
    if (lane == 0) {
      rowcnt[row] = min(wbase, CAP);
      dinv[row] = rsqrtf((float)wbase + 1.0f);
    }
  }
}

// ---------------------------------------------------------------------------
// Kernel B (fused gc1+relu+gc2-matmul): h_row = relu(A_norm @ xw + b1) in LDS,
// then hw_row = h_row @ W2 via per-block partial reduction. Block = one row.
// ---------------------------------------------------------------------------
__global__ __launch_bounds__(128) void kB(const float* __restrict__ xw,
                                          const int* __restrict__ rowcnt,
                                          const int* __restrict__ cols,
                                          const float* __restrict__ dinv,
                                          const float* __restrict__ b1,
                                          const float* __restrict__ W2,
                                          float* __restrict__ hw) {
  __shared__ int   sj[CAP];
  __shared__ float sw[CAP];
  __shared__ float sh[NHID];
  __shared__ float part[128];
  int row = blockIdx.x;
  int c = threadIdx.x;
  int cnt = rowcnt[row];
  const int* crow = cols + (size_t)row * CAP;
  if (c < cnt) { int j = crow[c]; sj[c] = j; sw[c] = dinv[j]; }
  __syncthreads();
  float di = dinv[row];
  float acc = di * xw[(size_t)row * NHID + c];   // self-loop (I) term
  int e = 0;
  for (; e + 4 <= cnt; e += 4) {
    int j0 = sj[e], j1 = sj[e + 1], j2 = sj[e + 2], j3 = sj[e + 3];
    float w0 = sw[e], w1 = sw[e + 1], w2 = sw[e + 2], w3 = sw[e + 3];
    float v0 = xw[(size_t)j0 * NHID + c];
    float v1 = xw[(size_t)j1 * NHID + c];
    float v2 = xw[(size_t)j2 * NHID + c];
    float v3 = xw[(size_t)j3 * NHID + c];
    acc = fmaf(w0, v0, acc);
    acc = fmaf(w1, v1, acc);
    acc = fmaf(w2, v2, acc);
    acc = fmaf(w3, v3, acc);
  }
  for (; e < cnt; ++e) acc = fmaf(sw[e], xw[(size_t)sj[e] * NHID + c], acc);
  float h = fmaxf(fmaf(di, acc, b1[c]), 0.0f);
  sh[c] = h;
  __syncthreads();
  int cc = c & 15, seg = c >> 4;
  float pacc = 0.0f;
#pragma unroll
  for (int kk = 0; kk < 16; ++kk) {
    int k = seg * 16 + kk;
    pacc = fmaf(sh[k], W2[(size_t)k * NCLASS + cc], pacc);
  }
  part[c] = pacc;
  __syncthreads();
  if (c < 16) {
    float s = 0.0f;
#pragma unroll
    for (int sg = 0; sg < 8; ++sg) s += part[c + 16 * sg];
    hw[(size_t)row * NCLASS + c] = s;
  }
}

// ---------------------------------------------------------------------------
// Kernel C: out = log_softmax(A_norm @ hw + b2). One wave per row; 4 edge
// slots x 16 classes per lane; (j,w) register-cached + shfl broadcast.
// ---------------------------------------------------------------------------
__global__ __launch_bounds__(256) void kC(const float* __restrict__ hw,
                                          const int* __restrict__ rowcnt,
                                          const int* __restrict__ cols,
                                          const float* __restrict__ dinv,
                                          const float* __restrict__ b2,
                                          float* __restrict__ out) {
  int lane = threadIdx.x & 63;
  int wid = threadIdx.x >> 6;
  int row = blockIdx.x * 4 + wid;
  int cnt = rowcnt[row];
  const int* crow = cols + (size_t)row * CAP;
  int jA = 0; float wA = 0.0f;
  if (lane < cnt) { jA = crow[lane]; wA = dinv[jA]; }
  int jB = 0; float wB = 0.0f;
  if (lane + 64 < cnt) { jB = crow[lane + 64]; wB = dinv[jB]; }
  int c = lane & 15, slot = lane >> 4;
  float acc = 0.0f;
  for (int e0 = 0; e0 < cnt; e0 += 4) {
    int e = e0 + slot;
    int   j1 = __shfl(jA, e & 63);
    float w1 = __shfl(wA, e & 63);
    int   j2 = __shfl(jB, (e - 64) & 63);
    float w2 = __shfl(wB, (e - 64) & 63);
    int   j = (e < 64) ? j1 : j2;
    float w = (e < 64) ? w1 : w2;
    if (e < cnt) acc = fmaf(w, hw[(size_t)j * NCLASS + c], acc);
  }
  acc += __shfl_xor(acc, 16);
  acc += __shfl_xor(acc, 32);
  float di = dinv[row];
  float self = hw[(size_t)row * NCLASS + c];
  float v = fmaf(di, acc, fmaf(di * di, self, b2[c]));
  float m = v;
#pragma unroll
  for (int o = 8; o >= 1; o >>= 1) m = fmaxf(m, __shfl_xor(m, o, 16));
  float ex = __expf(v - m);
  float s = ex;
#pragma unroll
  for (int o = 8; o >= 1; o >>= 1) s += __shfl_xor(s, o, 16);
  if (slot == 0) out[(size_t)row * NCLASS + c] = v - m - logf(s);
}

// ---------------------------------------------------------------------------

extern "C" void kernel_launch(void* const* d_in, const int* in_sizes, int n_in,
                              void* d_out, int out_size, void* d_ws, size_t ws_size,
                              hipStream_t stream) {
  const float* x   = (const float*)d_in[0];
  const float* adj = (const float*)d_in[1];
  const float* W1  = (const float*)d_in[2];
  const float* b1  = (const float*)d_in[3];
  const float* W2  = (const float*)d_in[4];
  const float* b2  = (const float*)d_in[5];
  float* out = (float*)d_out;

  char* ws = (char*)d_ws;
  float* dinv = (float*)(ws);                      // 32 KB
  int*   rowc = (int*)(ws + 32768);                // 32 KB
  int*   cols = (int*)(ws + 65536);                // 4 MB
  float* xw   = (float*)(ws + 65536 + 4194304);    // 4 MB
  float* hw   = (float*)(ws + 65536 + 8388608);    // 512 KB

  kA<<<K2B + K1B, 256, 0, stream>>>(adj, x, W1, rowc, cols, dinv, xw);
  kB<<<NN, 128, 0, stream>>>(xw, rowc, cols, dinv, b1, W2, hw);
  kC<<<NN / 4, 256, 0, stream>>>(hw, rowc, cols, dinv, b2, out);
}